// Round 6
// baseline (1114.180 us; speedup 1.0000x reference)
//
#include <hip/hip_runtime.h>
#include <math.h>

#define NZTOT   262144
#define MF      131072      /* NZTOT/2 */
#define KCUT    62584       /* first k with g_sq clamped to 1 is 62583; include it (value ~0) */
#define KWS     62592       /* padded stride for w_tilde */
#define DZ_F    0.1f
#define GC_F    15.0f

__device__ __forceinline__ int rev256(int k) {
  return ((k & 3) << 6) | (((k >> 2) & 3) << 4) | (((k >> 4) & 3) << 2) | ((k >> 6) & 3);
}
__device__ __forceinline__ int rev512(int k) {
  return ((k & 3) << 7) | (((k >> 2) & 3) << 5) | (((k >> 4) & 3) << 3) |
         (((k >> 6) & 3) << 1) | ((k >> 8) & 1);
}

// Fast CELU: max(x,0) + exp(min(x,0)) - 1, via v_exp_f32. ~1e-7 abs error.
__device__ __forceinline__ float celu_fast(float x) {
  float xm = fminf(x, 0.0f);
  float e = __builtin_amdgcn_exp2f(xm * 1.4426950408889634f) - 1.0f;
  return fmaxf(x, 0.0f) + e;
}

// In-LDS radix-4 DIF FFT over one contiguous line of L complex values.
// TPL threads per line, p = thread index within line. Output is digit-reversed.
template<int L, int TPL, int SIGN>
__device__ __forceinline__ void dif_fft_line(float2* v, int p) {
  #pragma unroll
  for (int s = 0; (L >> (2 * s)) >= 4; ++s) {
    const int B = L >> (2 * s);
    const int Q = B >> 2;
    #pragma unroll
    for (int it = 0; it < (L / 4) / TPL; ++it) {
      int i = p + it * TPL;
      int g = i / Q;
      int j = i - g * Q;
      int base = g * B + j;
      float2 a0 = v[base], a1 = v[base + Q], a2 = v[base + 2 * Q], a3 = v[base + 3 * Q];
      float t0x = a0.x + a2.x, t0y = a0.y + a2.y;
      float t1x = a0.x - a2.x, t1y = a0.y - a2.y;
      float t2x = a1.x + a3.x, t2y = a1.y + a3.y;
      float dx = a1.x - a3.x, dy = a1.y - a3.y;
      float t3x = -(float)SIGN * dy, t3y = (float)SIGN * dx;   /* sign*i*(a1-a3) */
      float y0x = t0x + t2x, y0y = t0y + t2y;
      float y2x = t0x - t2x, y2y = t0y - t2y;
      float y1x = t1x + t3x, y1y = t1y + t3y;
      float y3x = t1x - t3x, y3y = t1y - t3y;
      float s1, c1;
      sincospif((float)SIGN * 2.0f * (float)j / (float)B, &s1, &c1);
      float c2 = c1 * c1 - s1 * s1, s2 = 2.0f * c1 * s1;
      float c3 = c1 * c2 - s1 * s2, s3 = c1 * s2 + s1 * c2;
      v[base] = make_float2(y0x, y0y);
      v[base + Q]     = make_float2(y1x * c1 - y1y * s1, y1x * s1 + y1y * c1);
      v[base + 2 * Q] = make_float2(y2x * c2 - y2y * s2, y2x * s2 + y2y * c2);
      v[base + 3 * Q] = make_float2(y3x * c3 - y3y * s3, y3x * s3 + y3y * c3);
    }
    __syncthreads();
  }
  if (L == 512) {  /* trailing radix-2 stage */
    #pragma unroll
    for (int it = 0; it < (L / 2) / TPL; ++it) {
      int i = p + it * TPL;
      float2 a0 = v[2 * i], a1 = v[2 * i + 1];
      v[2 * i]     = make_float2(a0.x + a1.x, a0.y + a1.y);
      v[2 * i + 1] = make_float2(a0.x - a1.x, a0.y - a1.y);
    }
    __syncthreads();
  }
}

// Four-step stage 1: for each n1 in [0,512): length-256 DFT over n2 (input stride 512),
// apply twiddle e^{SIGN*2pi*i*n1*k2/M}, write transposed G[k2*512 + n1] (natural k2).
template<int SIGN>
__global__ __launch_bounds__(256) void k_fft_stage1(const float2* __restrict__ gin,
                                                    float2* __restrict__ gout) {
  __shared__ float2 tile[16][258];
  const float2* in = gin + (size_t)blockIdx.y * MF;
  float2* out = gout + (size_t)blockIdx.y * MF;
  int c16 = blockIdx.x * 16;
  int tx = threadIdx.x & 15, ty = threadIdx.x >> 4;
  #pragma unroll
  for (int j = 0; j < 16; ++j) {
    int n2 = ty + j * 16;
    tile[tx][n2] = in[(size_t)n2 * 512 + c16 + tx];
  }
  __syncthreads();
  dif_fft_line<256, 16, SIGN>(&tile[ty][0], tx);
  int n1 = c16 + tx;
  #pragma unroll
  for (int u = 0; u < 16; ++u) {
    int k2 = ty + u * 16;
    float2 vv = tile[tx][rev256(k2)];
    float s1, c1;
    sincospif((float)SIGN * 2.0f * (float)(n1 * k2) / (float)MF, &s1, &c1);
    out[(size_t)k2 * 512 + n1] = make_float2(vv.x * c1 - vv.y * s1, vv.x * s1 + vv.y * c1);
  }
}

// Four-step stage 2: for each k2: length-512 DFT over n1 (contiguous line in G).
// UNPERM=true  -> write natural order X[k1*256 + k2] (needed for spectral multiply)
// UNPERM=false -> write digit-reversed in-place order (order-agnostic consumer)
template<int SIGN, bool UNPERM>
__global__ __launch_bounds__(256) void k_fft_stage2(const float2* __restrict__ gin,
                                                    float2* __restrict__ gout) {
  __shared__ float2 tile[8][514];
  const float2* in = gin + (size_t)blockIdx.y * MF;
  float2* out = gout + (size_t)blockIdx.y * MF;
  int c8 = blockIdx.x * 8;
  #pragma unroll
  for (int j = 0; j < 16; ++j) {
    int flat = threadIdx.x + 256 * j;
    tile[flat >> 9][flat & 511] = in[(size_t)c8 * 512 + flat];
  }
  __syncthreads();
  dif_fft_line<512, 32, SIGN>(&tile[threadIdx.x >> 5][0], threadIdx.x & 31);
  if (UNPERM) {
    int sx = threadIdx.x & 7, sy = threadIdx.x >> 3;
    #pragma unroll
    for (int u = 0; u < 16; ++u) {
      int k1 = sy + 32 * u;
      out[(size_t)k1 * 256 + c8 + sx] = tile[sx][rev512(k1)];
    }
  } else {
    #pragma unroll
    for (int j = 0; j < 16; ++j) {
      int flat = threadIdx.x + 256 * j;
      out[(size_t)c8 * 512 + flat] = tile[flat >> 9][flat & 511];
    }
  }
}

// w_tilde[c][k] for k < KCUT (zero beyond cutoff, never stored/read there).
__global__ __launch_bounds__(256) void k_wtilde(
    const float* __restrict__ W0, const float* __restrict__ b0,
    const float* __restrict__ W1, const float* __restrict__ b1,
    const float* __restrict__ W2, const float* __restrict__ b2,
    float2* __restrict__ wt) {
  int k = blockIdx.x * 256 + threadIdx.x;
  if (k >= KCUT) return;
  const float GZSC = (float)(2.0 * 3.14159265358979323846 / 26214.4);
  float Gz = (float)k * GZSC;
  float g = Gz / GC_F;
  float gsq = fminf(g * g, 1.0f);
  float h1[64], h2[64];
  #pragma unroll
  for (int o = 0; o < 64; ++o) {
    float x = W0[o] * gsq + b0[o];
    h1[o] = x > 0.0f ? x : expm1f(x);
  }
  #pragma unroll
  for (int o = 0; o < 64; ++o) {
    float acc = b1[o];
    #pragma unroll
    for (int i = 0; i < 64; ++i) acc = fmaf(W1[o * 64 + i], h1[i], acc);
    h2[o] = acc > 0.0f ? acc : expm1f(acc);
  }
  float om = 1.0f - gsq;
  float fac2 = om * om;
  #pragma unroll
  for (int c = 0; c < 8; ++c) {
    float acc = b2[c];
    #pragma unroll
    for (int i = 0; i < 64; ++i) acc = fmaf(W2[c * 64 + i], h2[i], acc);
    const int P = c & 3;
    float gp = 1.0f;
    #pragma unroll
    for (int t = 0; t < P; ++t) gp *= gsq;
    const int GP = 2 * P + (c >= 4 ? 1 : 0);
    float prod = 1.0f;
    #pragma unroll
    for (int t = 0; t < 5; ++t) prod *= (float)(2 * GP + 2 * t + 1);
    float nrm = sqrtf(prod / 384.0f);
    if (c >= 4) nrm *= (1.0f / GC_F);
    float wv = acc * fac2 * gp * nrm;
    float2 z = (c < 4) ? make_float2(wv, 0.0f) : make_float2(0.0f, Gz * wv);
    wt[(size_t)c * KWS + k] = z;
  }
}

// Unpack rfft from packed forward FFT C, multiply by w_tilde, and re-pack the
// product spectrum for the packed inverse transform (includes 0.5/M scaling).
// Exploits Y[k]=0 for k>=KCUT (so the conj-partner term vanishes for k<=M/2).
__global__ __launch_bounds__(256) void k_specmul(const float2* __restrict__ C,
                                                 const float2* __restrict__ wt,
                                                 float2* __restrict__ Z) {
  int k = blockIdx.x * 256 + threadIdx.x;
  if (k > MF / 2) return;
  int b = blockIdx.y;
  const float2* Cb = C + (size_t)b * MF;
  const float SCL = 0.5f / (float)MF;
  if (k < KCUT) {
    float2 Ck = Cb[k];
    float2 Cm = Cb[(MF - k) & (MF - 1)];
    float sE, cE;
    sincospif((float)k * (1.0f / 131072.0f), &sE, &cE);   /* E = e^{2*pi*i*k/N} */
    float Ax = Ck.x + Cm.x, Ay = Ck.y - Cm.y;
    float Dx = Ck.x - Cm.x, Dy = Ck.y + Cm.y;
    float tx = cE * Dx + sE * Dy;
    float ty = cE * Dy - sE * Dx;
    float Xx = 0.5f * (Ax + ty);     /* X[k] = rfft(n)[k] */
    float Xy = 0.5f * (Ay - tx);
    float F1x = 1.0f - sE, F2x = 1.0f + sE;
    #pragma unroll
    for (int f = 0; f < 8; ++f) {
      float2 w = wt[(size_t)f * KWS + k];
      float Yx = w.x * Xx - w.y * Xy;
      float Yy = w.x * Xy + w.y * Xx;
      size_t base = ((size_t)(f * 8 + b)) * MF;
      Z[base + k] = make_float2(SCL * (Yx * F1x - Yy * cE), SCL * (Yx * cE + Yy * F1x));
      if (k > 0)
        Z[base + MF - k] = make_float2(SCL * (Yx * F2x + Yy * cE), SCL * (Yx * cE - Yy * F2x));
    }
  } else {
    #pragma unroll
    for (int f = 0; f < 8; ++f) {
      size_t base = ((size_t)(f * 8 + b)) * MF;
      Z[base + k] = make_float2(0.0f, 0.0f);
      Z[base + MF - k] = make_float2(0.0f, 0.0f);
    }
  }
}

// Pointwise: 14 scalars -> MLP -> weighted sum; block partial sums per batch.
// Register-lean: layer-3 fused into the layer-2 loop via
//   tot += h2_o * (sum_c W2[c][o]*sc[c]);  no h2[] array is ever held.
__global__ __launch_bounds__(256, 5) void k_mlpsum(
    const float* __restrict__ conv,
    const float* __restrict__ W0, const float* __restrict__ b0,
    const float* __restrict__ W1, const float* __restrict__ b1,
    const float* __restrict__ W2, const float* __restrict__ b2,
    float* __restrict__ partial) {
  int b = blockIdx.y;
  size_t z = (size_t)blockIdx.x * 256 + threadIdx.x;
  float sc[14];
  #pragma unroll
  for (int c = 0; c < 4; ++c) sc[c] = conv[(size_t)(c * 8 + b) * NZTOT + z];
  float o0 = conv[(size_t)(4 * 8 + b) * NZTOT + z];
  float o1 = conv[(size_t)(5 * 8 + b) * NZTOT + z];
  float o2 = conv[(size_t)(6 * 8 + b) * NZTOT + z];
  float o3 = conv[(size_t)(7 * 8 + b) * NZTOT + z];
  sc[4] = o0 * o0; sc[5] = o0 * o1; sc[6] = o0 * o2; sc[7] = o0 * o3;
  sc[8] = o1 * o1; sc[9] = o1 * o2; sc[10] = o1 * o3;
  sc[11] = o2 * o2; sc[12] = o2 * o3;
  sc[13] = o3 * o3;

  float h1[64];
  #pragma unroll
  for (int o = 0; o < 64; ++o) {
    float acc = b0[o];
    #pragma unroll
    for (int i = 0; i < 14; ++i) acc = fmaf(W0[o * 14 + i], sc[i], acc);
    h1[o] = celu_fast(acc);
  }

  float tot = 0.0f;
  #pragma unroll
  for (int c = 0; c < 14; ++c) tot = fmaf(sc[c], b2[c], tot);

  #pragma unroll
  for (int o = 0; o < 64; ++o) {
    float acc = b1[o];
    #pragma unroll
    for (int i = 0; i < 64; ++i) acc = fmaf(W1[o * 64 + i], h1[i], acc);
    float h2o = celu_fast(acc);
    float u = 0.0f;
    #pragma unroll
    for (int c = 0; c < 14; ++c) u = fmaf(W2[c * 64 + o], sc[c], u);
    tot = fmaf(h2o, u, tot);
  }

  __shared__ float red[256];
  red[threadIdx.x] = tot;
  __syncthreads();
  for (int s = 128; s > 0; s >>= 1) {
    if (threadIdx.x < s) red[threadIdx.x] += red[threadIdx.x + s];
    __syncthreads();
  }
  if (threadIdx.x == 0) partial[b * 1024 + blockIdx.x] = red[0];
}

__global__ __launch_bounds__(256) void k_reduce(const float* __restrict__ partial,
                                                float* __restrict__ out) {
  __shared__ float red[256];
  int b = blockIdx.x;
  float acc = 0.0f;
  #pragma unroll
  for (int j = 0; j < 4; ++j) acc += partial[b * 1024 + threadIdx.x + 256 * j];
  red[threadIdx.x] = acc;
  __syncthreads();
  for (int s = 128; s > 0; s >>= 1) {
    if (threadIdx.x < s) red[threadIdx.x] += red[threadIdx.x + s];
    __syncthreads();
  }
  if (threadIdx.x == 0) out[b] = DZ_F * red[0];
}

extern "C" void kernel_launch(void* const* d_in, const int* in_sizes, int n_in,
                              void* d_out, int out_size, void* d_ws, size_t ws_size,
                              hipStream_t stream) {
  (void)in_sizes; (void)n_in; (void)out_size; (void)ws_size;
  const float2* nP = (const float2*)d_in[0];   /* n viewed as packed complex, per batch MF */
  const float* wW0 = (const float*)d_in[1];
  const float* wb0 = (const float*)d_in[2];
  const float* wW1 = (const float*)d_in[3];
  const float* wb1 = (const float*)d_in[4];
  const float* wW2 = (const float*)d_in[5];
  const float* wb2 = (const float*)d_in[6];
  const float* fW0 = (const float*)d_in[7];
  const float* fb0 = (const float*)d_in[8];
  const float* fW1 = (const float*)d_in[9];
  const float* fb1 = (const float*)d_in[10];
  const float* fW2 = (const float*)d_in[11];
  const float* fb2 = (const float*)d_in[12];

  /* workspace layout (float2 units): Gf[8*MF] | C[8*MF] | wt[8*KWS] | Z[64*MF] | T[64*MF] | partial */
  float2* Gf = (float2*)d_ws;
  float2* C  = Gf + (size_t)8 * MF;
  float2* wt = C + (size_t)8 * MF;
  float2* Z  = wt + (size_t)8 * KWS;
  float2* T  = Z + (size_t)64 * MF;
  float*  partial = (float*)(T + (size_t)64 * MF);
  float*  conv = (float*)Z;   /* conv aliases Z: Z fully consumed by inverse stage 1 */

  k_wtilde<<<dim3((KCUT + 255) / 256), dim3(256), 0, stream>>>(wW0, wb0, wW1, wb1, wW2, wb2, wt);
  k_fft_stage1<(-1)><<<dim3(32, 8), dim3(256), 0, stream>>>(nP, Gf);
  k_fft_stage2<(-1), true><<<dim3(32, 8), dim3(256), 0, stream>>>(Gf, C);
  k_specmul<<<dim3(257, 8), dim3(256), 0, stream>>>(C, wt, Z);
  k_fft_stage1<1><<<dim3(32, 64), dim3(256), 0, stream>>>(Z, T);
  k_fft_stage2<1, false><<<dim3(32, 64), dim3(256), 0, stream>>>(T, (float2*)conv);
  k_mlpsum<<<dim3(1024, 8), dim3(256), 0, stream>>>(conv, fW0, fb0, fW1, fb1, fW2, fb2, partial);
  k_reduce<<<dim3(8), dim3(256), 0, stream>>>(partial, (float*)d_out);
}

// Round 8
// 633.673 us; speedup vs baseline: 1.7583x; 1.7583x over previous
//
#include <hip/hip_runtime.h>
#include <math.h>

#define NZTOT   262144
#define MF      131072      /* NZTOT/2 */
#define KCUT    62584       /* first k with g_sq clamped to 1 is 62583; include it (value ~0) */
#define KWS     62592       /* padded stride for w_tilde */
#define DZ_F    0.1f
#define GC_F    15.0f

__device__ __forceinline__ int rev256(int k) {
  return ((k & 3) << 6) | (((k >> 2) & 3) << 4) | (((k >> 4) & 3) << 2) | ((k >> 6) & 3);
}
__device__ __forceinline__ int rev512(int k) {
  return ((k & 3) << 7) | (((k >> 2) & 3) << 5) | (((k >> 4) & 3) << 3) |
         (((k >> 6) & 3) << 1) | ((k >> 8) & 1);
}

// Fast CELU: max(x,0) + exp(min(x,0)) - 1, via v_exp_f32. ~1e-7 abs error.
__device__ __forceinline__ float celu_fast(float x) {
  float xm = fminf(x, 0.0f);
  float e = __builtin_amdgcn_exp2f(xm * 1.4426950408889634f) - 1.0f;
  return fmaxf(x, 0.0f) + e;
}

// In-LDS radix-4 DIF FFT over one contiguous line of L complex values.
// TPL threads per line, p = thread index within line. Output is digit-reversed.
template<int L, int TPL, int SIGN>
__device__ __forceinline__ void dif_fft_line(float2* v, int p) {
  #pragma unroll
  for (int s = 0; (L >> (2 * s)) >= 4; ++s) {
    const int B = L >> (2 * s);
    const int Q = B >> 2;
    #pragma unroll
    for (int it = 0; it < (L / 4) / TPL; ++it) {
      int i = p + it * TPL;
      int g = i / Q;
      int j = i - g * Q;
      int base = g * B + j;
      float2 a0 = v[base], a1 = v[base + Q], a2 = v[base + 2 * Q], a3 = v[base + 3 * Q];
      float t0x = a0.x + a2.x, t0y = a0.y + a2.y;
      float t1x = a0.x - a2.x, t1y = a0.y - a2.y;
      float t2x = a1.x + a3.x, t2y = a1.y + a3.y;
      float dx = a1.x - a3.x, dy = a1.y - a3.y;
      float t3x = -(float)SIGN * dy, t3y = (float)SIGN * dx;   /* sign*i*(a1-a3) */
      float y0x = t0x + t2x, y0y = t0y + t2y;
      float y2x = t0x - t2x, y2y = t0y - t2y;
      float y1x = t1x + t3x, y1y = t1y + t3y;
      float y3x = t1x - t3x, y3y = t1y - t3y;
      float s1, c1;
      sincospif((float)SIGN * 2.0f * (float)j / (float)B, &s1, &c1);
      float c2 = c1 * c1 - s1 * s1, s2 = 2.0f * c1 * s1;
      float c3 = c1 * c2 - s1 * s2, s3 = c1 * s2 + s1 * c2;
      v[base] = make_float2(y0x, y0y);
      v[base + Q]     = make_float2(y1x * c1 - y1y * s1, y1x * s1 + y1y * c1);
      v[base + 2 * Q] = make_float2(y2x * c2 - y2y * s2, y2x * s2 + y2y * c2);
      v[base + 3 * Q] = make_float2(y3x * c3 - y3y * s3, y3x * s3 + y3y * c3);
    }
    __syncthreads();
  }
  if (L == 512) {  /* trailing radix-2 stage */
    #pragma unroll
    for (int it = 0; it < (L / 2) / TPL; ++it) {
      int i = p + it * TPL;
      float2 a0 = v[2 * i], a1 = v[2 * i + 1];
      v[2 * i]     = make_float2(a0.x + a1.x, a0.y + a1.y);
      v[2 * i + 1] = make_float2(a0.x - a1.x, a0.y - a1.y);
    }
    __syncthreads();
  }
}

// Four-step stage 1: for each n1 in [0,512): length-256 DFT over n2 (input stride 512),
// apply twiddle e^{SIGN*2pi*i*n1*k2/M}, write transposed G[k2*512 + n1] (natural k2).
template<int SIGN>
__global__ __launch_bounds__(256) void k_fft_stage1(const float2* __restrict__ gin,
                                                    float2* __restrict__ gout) {
  __shared__ float2 tile[16][258];
  const float2* in = gin + (size_t)blockIdx.y * MF;
  float2* out = gout + (size_t)blockIdx.y * MF;
  int c16 = blockIdx.x * 16;
  int tx = threadIdx.x & 15, ty = threadIdx.x >> 4;
  #pragma unroll
  for (int j = 0; j < 16; ++j) {
    int n2 = ty + j * 16;
    tile[tx][n2] = in[(size_t)n2 * 512 + c16 + tx];
  }
  __syncthreads();
  dif_fft_line<256, 16, SIGN>(&tile[ty][0], tx);
  int n1 = c16 + tx;
  #pragma unroll
  for (int u = 0; u < 16; ++u) {
    int k2 = ty + u * 16;
    float2 vv = tile[tx][rev256(k2)];
    float s1, c1;
    sincospif((float)SIGN * 2.0f * (float)(n1 * k2) / (float)MF, &s1, &c1);
    out[(size_t)k2 * 512 + n1] = make_float2(vv.x * c1 - vv.y * s1, vv.x * s1 + vv.y * c1);
  }
}

// Four-step stage 2: for each k2: length-512 DFT over n1 (contiguous line in G).
// UNPERM=true  -> write natural order X[k1*256 + k2] (needed for spectral multiply)
// UNPERM=false -> write digit-reversed in-place order (order-agnostic consumer)
template<int SIGN, bool UNPERM>
__global__ __launch_bounds__(256) void k_fft_stage2(const float2* __restrict__ gin,
                                                    float2* __restrict__ gout) {
  __shared__ float2 tile[8][514];
  const float2* in = gin + (size_t)blockIdx.y * MF;
  float2* out = gout + (size_t)blockIdx.y * MF;
  int c8 = blockIdx.x * 8;
  #pragma unroll
  for (int j = 0; j < 16; ++j) {
    int flat = threadIdx.x + 256 * j;
    tile[flat >> 9][flat & 511] = in[(size_t)c8 * 512 + flat];
  }
  __syncthreads();
  dif_fft_line<512, 32, SIGN>(&tile[threadIdx.x >> 5][0], threadIdx.x & 31);
  if (UNPERM) {
    int sx = threadIdx.x & 7, sy = threadIdx.x >> 3;
    #pragma unroll
    for (int u = 0; u < 16; ++u) {
      int k1 = sy + 32 * u;
      out[(size_t)k1 * 256 + c8 + sx] = tile[sx][rev512(k1)];
    }
  } else {
    #pragma unroll
    for (int j = 0; j < 16; ++j) {
      int flat = threadIdx.x + 256 * j;
      out[(size_t)c8 * 512 + flat] = tile[flat >> 9][flat & 511];
    }
  }
}

// w_tilde[c][k] for k < KCUT (zero beyond cutoff, never stored/read there).
__global__ __launch_bounds__(256) void k_wtilde(
    const float* __restrict__ W0, const float* __restrict__ b0,
    const float* __restrict__ W1, const float* __restrict__ b1,
    const float* __restrict__ W2, const float* __restrict__ b2,
    float2* __restrict__ wt) {
  int k = blockIdx.x * 256 + threadIdx.x;
  if (k >= KCUT) return;
  const float GZSC = (float)(2.0 * 3.14159265358979323846 / 26214.4);
  float Gz = (float)k * GZSC;
  float g = Gz / GC_F;
  float gsq = fminf(g * g, 1.0f);
  float h1[64], h2[64];
  #pragma unroll
  for (int o = 0; o < 64; ++o) {
    float x = W0[o] * gsq + b0[o];
    h1[o] = x > 0.0f ? x : expm1f(x);
  }
  #pragma unroll
  for (int o = 0; o < 64; ++o) {
    float acc = b1[o];
    #pragma unroll
    for (int i = 0; i < 64; ++i) acc = fmaf(W1[o * 64 + i], h1[i], acc);
    h2[o] = acc > 0.0f ? acc : expm1f(acc);
  }
  float om = 1.0f - gsq;
  float fac2 = om * om;
  #pragma unroll
  for (int c = 0; c < 8; ++c) {
    float acc = b2[c];
    #pragma unroll
    for (int i = 0; i < 64; ++i) acc = fmaf(W2[c * 64 + i], h2[i], acc);
    const int P = c & 3;
    float gp = 1.0f;
    #pragma unroll
    for (int t = 0; t < P; ++t) gp *= gsq;
    const int GP = 2 * P + (c >= 4 ? 1 : 0);
    float prod = 1.0f;
    #pragma unroll
    for (int t = 0; t < 5; ++t) prod *= (float)(2 * GP + 2 * t + 1);
    float nrm = sqrtf(prod / 384.0f);
    if (c >= 4) nrm *= (1.0f / GC_F);
    float wv = acc * fac2 * gp * nrm;
    float2 z = (c < 4) ? make_float2(wv, 0.0f) : make_float2(0.0f, Gz * wv);
    wt[(size_t)c * KWS + k] = z;
  }
}

// Unpack rfft from packed forward FFT C, multiply by w_tilde, and re-pack the
// product spectrum for the packed inverse transform (includes 0.5/M scaling).
// Exploits Y[k]=0 for k>=KCUT (so the conj-partner term vanishes for k<=M/2).
__global__ __launch_bounds__(256) void k_specmul(const float2* __restrict__ C,
                                                 const float2* __restrict__ wt,
                                                 float2* __restrict__ Z) {
  int k = blockIdx.x * 256 + threadIdx.x;
  if (k > MF / 2) return;
  int b = blockIdx.y;
  const float2* Cb = C + (size_t)b * MF;
  const float SCL = 0.5f / (float)MF;
  if (k < KCUT) {
    float2 Ck = Cb[k];
    float2 Cm = Cb[(MF - k) & (MF - 1)];
    float sE, cE;
    sincospif((float)k * (1.0f / 131072.0f), &sE, &cE);   /* E = e^{2*pi*i*k/N} */
    float Ax = Ck.x + Cm.x, Ay = Ck.y - Cm.y;
    float Dx = Ck.x - Cm.x, Dy = Ck.y + Cm.y;
    float tx = cE * Dx + sE * Dy;
    float ty = cE * Dy - sE * Dx;
    float Xx = 0.5f * (Ax + ty);     /* X[k] = rfft(n)[k] */
    float Xy = 0.5f * (Ay - tx);
    float F1x = 1.0f - sE, F2x = 1.0f + sE;
    #pragma unroll
    for (int f = 0; f < 8; ++f) {
      float2 w = wt[(size_t)f * KWS + k];
      float Yx = w.x * Xx - w.y * Xy;
      float Yy = w.x * Xy + w.y * Xx;
      size_t base = ((size_t)(f * 8 + b)) * MF;
      Z[base + k] = make_float2(SCL * (Yx * F1x - Yy * cE), SCL * (Yx * cE + Yy * F1x));
      if (k > 0)
        Z[base + MF - k] = make_float2(SCL * (Yx * F2x + Yy * cE), SCL * (Yx * cE - Yy * F2x));
    }
  } else {
    #pragma unroll
    for (int f = 0; f < 8; ++f) {
      size_t base = ((size_t)(f * 8 + b)) * MF;
      Z[base + k] = make_float2(0.0f, 0.0f);
      Z[base + MF - k] = make_float2(0.0f, 0.0f);
    }
  }
}

// Pointwise: 14 scalars -> MLP -> weighted sum; block partial sums per batch.
// Register-lean: layer-3 fused into the layer-2 loop via
//   tot += h2_o * (sum_c W2[c][o]*sc[c]);  no h2[] array is ever held.
// __launch_bounds__(256, 4): VGPR cap 128 — fits h1[64]+sc[14]+temps with NO
// spill (the (256,5) cap of ~102 forced VGPR down to 44 and ~2.5x'd the VALU
// instruction count; 946us vs 713us baseline — measured R1).
__global__ __launch_bounds__(256, 4) void k_mlpsum(
    const float* __restrict__ conv,
    const float* __restrict__ W0, const float* __restrict__ b0,
    const float* __restrict__ W1, const float* __restrict__ b1,
    const float* __restrict__ W2, const float* __restrict__ b2,
    float* __restrict__ partial) {
  int b = blockIdx.y;
  size_t z = (size_t)blockIdx.x * 256 + threadIdx.x;
  float sc[14];
  #pragma unroll
  for (int c = 0; c < 4; ++c) sc[c] = conv[(size_t)(c * 8 + b) * NZTOT + z];
  float o0 = conv[(size_t)(4 * 8 + b) * NZTOT + z];
  float o1 = conv[(size_t)(5 * 8 + b) * NZTOT + z];
  float o2 = conv[(size_t)(6 * 8 + b) * NZTOT + z];
  float o3 = conv[(size_t)(7 * 8 + b) * NZTOT + z];
  sc[4] = o0 * o0; sc[5] = o0 * o1; sc[6] = o0 * o2; sc[7] = o0 * o3;
  sc[8] = o1 * o1; sc[9] = o1 * o2; sc[10] = o1 * o3;
  sc[11] = o2 * o2; sc[12] = o2 * o3;
  sc[13] = o3 * o3;

  float h1[64];
  #pragma unroll
  for (int o = 0; o < 64; ++o) {
    float acc = b0[o];
    #pragma unroll
    for (int i = 0; i < 14; ++i) acc = fmaf(W0[o * 14 + i], sc[i], acc);
    h1[o] = celu_fast(acc);
  }

  float tot = 0.0f;
  #pragma unroll
  for (int c = 0; c < 14; ++c) tot = fmaf(sc[c], b2[c], tot);

  #pragma unroll
  for (int o = 0; o < 64; ++o) {
    float acc = b1[o];
    #pragma unroll
    for (int i = 0; i < 64; ++i) acc = fmaf(W1[o * 64 + i], h1[i], acc);
    float h2o = celu_fast(acc);
    float u = 0.0f;
    #pragma unroll
    for (int c = 0; c < 14; ++c) u = fmaf(W2[c * 64 + o], sc[c], u);
    tot = fmaf(h2o, u, tot);
  }

  __shared__ float red[256];
  red[threadIdx.x] = tot;
  __syncthreads();
  for (int s = 128; s > 0; s >>= 1) {
    if (threadIdx.x < s) red[threadIdx.x] += red[threadIdx.x + s];
    __syncthreads();
  }
  if (threadIdx.x == 0) partial[b * 1024 + blockIdx.x] = red[0];
}

__global__ __launch_bounds__(256) void k_reduce(const float* __restrict__ partial,
                                                float* __restrict__ out) {
  __shared__ float red[256];
  int b = blockIdx.x;
  float acc = 0.0f;
  #pragma unroll
  for (int j = 0; j < 4; ++j) acc += partial[b * 1024 + threadIdx.x + 256 * j];
  red[threadIdx.x] = acc;
  __syncthreads();
  for (int s = 128; s > 0; s >>= 1) {
    if (threadIdx.x < s) red[threadIdx.x] += red[threadIdx.x + s];
    __syncthreads();
  }
  if (threadIdx.x == 0) out[b] = DZ_F * red[0];
}

extern "C" void kernel_launch(void* const* d_in, const int* in_sizes, int n_in,
                              void* d_out, int out_size, void* d_ws, size_t ws_size,
                              hipStream_t stream) {
  (void)in_sizes; (void)n_in; (void)out_size; (void)ws_size;
  const float2* nP = (const float2*)d_in[0];   /* n viewed as packed complex, per batch MF */
  const float* wW0 = (const float*)d_in[1];
  const float* wb0 = (const float*)d_in[2];
  const float* wW1 = (const float*)d_in[3];
  const float* wb1 = (const float*)d_in[4];
  const float* wW2 = (const float*)d_in[5];
  const float* wb2 = (const float*)d_in[6];
  const float* fW0 = (const float*)d_in[7];
  const float* fb0 = (const float*)d_in[8];
  const float* fW1 = (const float*)d_in[9];
  const float* fb1 = (const float*)d_in[10];
  const float* fW2 = (const float*)d_in[11];
  const float* fb2 = (const float*)d_in[12];

  /* workspace layout (float2 units): Gf[8*MF] | C[8*MF] | wt[8*KWS] | Z[64*MF] | T[64*MF] | partial */
  float2* Gf = (float2*)d_ws;
  float2* C  = Gf + (size_t)8 * MF;
  float2* wt = C + (size_t)8 * MF;
  float2* Z  = wt + (size_t)8 * KWS;
  float2* T  = Z + (size_t)64 * MF;
  float*  partial = (float*)(T + (size_t)64 * MF);
  float*  conv = (float*)Z;   /* conv aliases Z: Z fully consumed by inverse stage 1 */

  k_wtilde<<<dim3((KCUT + 255) / 256), dim3(256), 0, stream>>>(wW0, wb0, wW1, wb1, wW2, wb2, wt);
  k_fft_stage1<(-1)><<<dim3(32, 8), dim3(256), 0, stream>>>(nP, Gf);
  k_fft_stage2<(-1), true><<<dim3(32, 8), dim3(256), 0, stream>>>(Gf, C);
  k_specmul<<<dim3(257, 8), dim3(256), 0, stream>>>(C, wt, Z);
  k_fft_stage1<1><<<dim3(32, 64), dim3(256), 0, stream>>>(Z, T);
  k_fft_stage2<1, false><<<dim3(32, 64), dim3(256), 0, stream>>>(T, (float2*)conv);
  k_mlpsum<<<dim3(1024, 8), dim3(256), 0, stream>>>(conv, fW0, fb0, fW1, fb1, fW2, fb2, partial);
  k_reduce<<<dim3(8), dim3(256), 0, stream>>>(partial, (float*)d_out);
}

// Round 9
// 547.958 us; speedup vs baseline: 2.0333x; 1.1564x over previous
//
#include <hip/hip_runtime.h>
#include <math.h>

#define NZTOT   262144
#define MF      131072      /* NZTOT/2 */
#define KCUT    62584       /* first k with g_sq clamped to 1 is 62583; include it (value ~0) */
#define KWS     62592       /* padded stride for w_tilde */
#define DZ_F    0.1f
#define GC_F    15.0f

typedef float v2f __attribute__((ext_vector_type(2)));

__device__ __forceinline__ int rev256(int k) {
  return ((k & 3) << 6) | (((k >> 2) & 3) << 4) | (((k >> 4) & 3) << 2) | ((k >> 6) & 3);
}
__device__ __forceinline__ int rev512(int k) {
  return ((k & 3) << 7) | (((k >> 2) & 3) << 5) | (((k >> 4) & 3) << 3) |
         (((k >> 6) & 3) << 1) | ((k >> 8) & 1);
}

// Fast CELU: max(x,0) + exp(min(x,0)) - 1, via v_exp_f32. ~1e-7 abs error.
__device__ __forceinline__ float celu_fast(float x) {
  float xm = fminf(x, 0.0f);
  float e = __builtin_amdgcn_exp2f(xm * 1.4426950408889634f) - 1.0f;
  return fmaxf(x, 0.0f) + e;
}

// Packed dual FMA (VOP3P). Weight operand is wave-uniform -> SGPR pair ("s"),
// activations/accumulator in VGPR pairs. 2 fp32 FMAs per instruction: this is
// the only path to the 157 TF fp32 vector rate (scalar v_fma caps at 78.6 TF).
__device__ __forceinline__ v2f pkfma_s(v2f w, v2f b, v2f c) {
  v2f d;
  asm("v_pk_fma_f32 %0, %1, %2, %3" : "=v"(d) : "s"(w), "v"(b), "v"(c));
  return d;
}

// In-LDS radix-4 DIF FFT over one contiguous line of L complex values.
// TPL threads per line, p = thread index within line. Output is digit-reversed.
template<int L, int TPL, int SIGN>
__device__ __forceinline__ void dif_fft_line(float2* v, int p) {
  #pragma unroll
  for (int s = 0; (L >> (2 * s)) >= 4; ++s) {
    const int B = L >> (2 * s);
    const int Q = B >> 2;
    #pragma unroll
    for (int it = 0; it < (L / 4) / TPL; ++it) {
      int i = p + it * TPL;
      int g = i / Q;
      int j = i - g * Q;
      int base = g * B + j;
      float2 a0 = v[base], a1 = v[base + Q], a2 = v[base + 2 * Q], a3 = v[base + 3 * Q];
      float t0x = a0.x + a2.x, t0y = a0.y + a2.y;
      float t1x = a0.x - a2.x, t1y = a0.y - a2.y;
      float t2x = a1.x + a3.x, t2y = a1.y + a3.y;
      float dx = a1.x - a3.x, dy = a1.y - a3.y;
      float t3x = -(float)SIGN * dy, t3y = (float)SIGN * dx;   /* sign*i*(a1-a3) */
      float y0x = t0x + t2x, y0y = t0y + t2y;
      float y2x = t0x - t2x, y2y = t0y - t2y;
      float y1x = t1x + t3x, y1y = t1y + t3y;
      float y3x = t1x - t3x, y3y = t1y - t3y;
      float s1, c1;
      sincospif((float)SIGN * 2.0f * (float)j / (float)B, &s1, &c1);
      float c2 = c1 * c1 - s1 * s1, s2 = 2.0f * c1 * s1;
      float c3 = c1 * c2 - s1 * s2, s3 = c1 * s2 + s1 * c2;
      v[base] = make_float2(y0x, y0y);
      v[base + Q]     = make_float2(y1x * c1 - y1y * s1, y1x * s1 + y1y * c1);
      v[base + 2 * Q] = make_float2(y2x * c2 - y2y * s2, y2x * s2 + y2y * c2);
      v[base + 3 * Q] = make_float2(y3x * c3 - y3y * s3, y3x * s3 + y3y * c3);
    }
    __syncthreads();
  }
  if (L == 512) {  /* trailing radix-2 stage */
    #pragma unroll
    for (int it = 0; it < (L / 2) / TPL; ++it) {
      int i = p + it * TPL;
      float2 a0 = v[2 * i], a1 = v[2 * i + 1];
      v[2 * i]     = make_float2(a0.x + a1.x, a0.y + a1.y);
      v[2 * i + 1] = make_float2(a0.x - a1.x, a0.y - a1.y);
    }
    __syncthreads();
  }
}

// Four-step stage 1: for each n1 in [0,512): length-256 DFT over n2 (input stride 512),
// apply twiddle e^{SIGN*2pi*i*n1*k2/M}, write transposed G[k2*512 + n1] (natural k2).
template<int SIGN>
__global__ __launch_bounds__(256) void k_fft_stage1(const float2* __restrict__ gin,
                                                    float2* __restrict__ gout) {
  __shared__ float2 tile[16][258];
  const float2* in = gin + (size_t)blockIdx.y * MF;
  float2* out = gout + (size_t)blockIdx.y * MF;
  int c16 = blockIdx.x * 16;
  int tx = threadIdx.x & 15, ty = threadIdx.x >> 4;
  #pragma unroll
  for (int j = 0; j < 16; ++j) {
    int n2 = ty + j * 16;
    tile[tx][n2] = in[(size_t)n2 * 512 + c16 + tx];
  }
  __syncthreads();
  dif_fft_line<256, 16, SIGN>(&tile[ty][0], tx);
  int n1 = c16 + tx;
  #pragma unroll
  for (int u = 0; u < 16; ++u) {
    int k2 = ty + u * 16;
    float2 vv = tile[tx][rev256(k2)];
    float s1, c1;
    sincospif((float)SIGN * 2.0f * (float)(n1 * k2) / (float)MF, &s1, &c1);
    out[(size_t)k2 * 512 + n1] = make_float2(vv.x * c1 - vv.y * s1, vv.x * s1 + vv.y * c1);
  }
}

// Four-step stage 2: for each k2: length-512 DFT over n1 (contiguous line in G).
// UNPERM=true  -> write natural order X[k1*256 + k2] (needed for spectral multiply)
// UNPERM=false -> write digit-reversed in-place order (order-agnostic consumer)
template<int SIGN, bool UNPERM>
__global__ __launch_bounds__(256) void k_fft_stage2(const float2* __restrict__ gin,
                                                    float2* __restrict__ gout) {
  __shared__ float2 tile[8][514];
  const float2* in = gin + (size_t)blockIdx.y * MF;
  float2* out = gout + (size_t)blockIdx.y * MF;
  int c8 = blockIdx.x * 8;
  #pragma unroll
  for (int j = 0; j < 16; ++j) {
    int flat = threadIdx.x + 256 * j;
    tile[flat >> 9][flat & 511] = in[(size_t)c8 * 512 + flat];
  }
  __syncthreads();
  dif_fft_line<512, 32, SIGN>(&tile[threadIdx.x >> 5][0], threadIdx.x & 31);
  if (UNPERM) {
    int sx = threadIdx.x & 7, sy = threadIdx.x >> 3;
    #pragma unroll
    for (int u = 0; u < 16; ++u) {
      int k1 = sy + 32 * u;
      out[(size_t)k1 * 256 + c8 + sx] = tile[sx][rev512(k1)];
    }
  } else {
    #pragma unroll
    for (int j = 0; j < 16; ++j) {
      int flat = threadIdx.x + 256 * j;
      out[(size_t)c8 * 512 + flat] = tile[flat >> 9][flat & 511];
    }
  }
}

// w_tilde[c][k] for k < KCUT (zero beyond cutoff, never stored/read there).
__global__ __launch_bounds__(256) void k_wtilde(
    const float* __restrict__ W0, const float* __restrict__ b0,
    const float* __restrict__ W1, const float* __restrict__ b1,
    const float* __restrict__ W2, const float* __restrict__ b2,
    float2* __restrict__ wt) {
  int k = blockIdx.x * 256 + threadIdx.x;
  if (k >= KCUT) return;
  const float GZSC = (float)(2.0 * 3.14159265358979323846 / 26214.4);
  float Gz = (float)k * GZSC;
  float g = Gz / GC_F;
  float gsq = fminf(g * g, 1.0f);
  float h1[64], h2[64];
  #pragma unroll
  for (int o = 0; o < 64; ++o) {
    float x = W0[o] * gsq + b0[o];
    h1[o] = x > 0.0f ? x : expm1f(x);
  }
  #pragma unroll
  for (int o = 0; o < 64; ++o) {
    float acc = b1[o];
    #pragma unroll
    for (int i = 0; i < 64; ++i) acc = fmaf(W1[o * 64 + i], h1[i], acc);
    h2[o] = acc > 0.0f ? acc : expm1f(acc);
  }
  float om = 1.0f - gsq;
  float fac2 = om * om;
  #pragma unroll
  for (int c = 0; c < 8; ++c) {
    float acc = b2[c];
    #pragma unroll
    for (int i = 0; i < 64; ++i) acc = fmaf(W2[c * 64 + i], h2[i], acc);
    const int P = c & 3;
    float gp = 1.0f;
    #pragma unroll
    for (int t = 0; t < P; ++t) gp *= gsq;
    const int GP = 2 * P + (c >= 4 ? 1 : 0);
    float prod = 1.0f;
    #pragma unroll
    for (int t = 0; t < 5; ++t) prod *= (float)(2 * GP + 2 * t + 1);
    float nrm = sqrtf(prod / 384.0f);
    if (c >= 4) nrm *= (1.0f / GC_F);
    float wv = acc * fac2 * gp * nrm;
    float2 z = (c < 4) ? make_float2(wv, 0.0f) : make_float2(0.0f, Gz * wv);
    wt[(size_t)c * KWS + k] = z;
  }
}

// Unpack rfft from packed forward FFT C, multiply by w_tilde, and re-pack the
// product spectrum for the packed inverse transform (includes 0.5/M scaling).
// Exploits Y[k]=0 for k>=KCUT (so the conj-partner term vanishes for k<=M/2).
__global__ __launch_bounds__(256) void k_specmul(const float2* __restrict__ C,
                                                 const float2* __restrict__ wt,
                                                 float2* __restrict__ Z) {
  int k = blockIdx.x * 256 + threadIdx.x;
  if (k > MF / 2) return;
  int b = blockIdx.y;
  const float2* Cb = C + (size_t)b * MF;
  const float SCL = 0.5f / (float)MF;
  if (k < KCUT) {
    float2 Ck = Cb[k];
    float2 Cm = Cb[(MF - k) & (MF - 1)];
    float sE, cE;
    sincospif((float)k * (1.0f / 131072.0f), &sE, &cE);   /* E = e^{2*pi*i*k/N} */
    float Ax = Ck.x + Cm.x, Ay = Ck.y - Cm.y;
    float Dx = Ck.x - Cm.x, Dy = Ck.y + Cm.y;
    float tx = cE * Dx + sE * Dy;
    float ty = cE * Dy - sE * Dx;
    float Xx = 0.5f * (Ax + ty);     /* X[k] = rfft(n)[k] */
    float Xy = 0.5f * (Ay - tx);
    float F1x = 1.0f - sE, F2x = 1.0f + sE;
    #pragma unroll
    for (int f = 0; f < 8; ++f) {
      float2 w = wt[(size_t)f * KWS + k];
      float Yx = w.x * Xx - w.y * Xy;
      float Yy = w.x * Xy + w.y * Xx;
      size_t base = ((size_t)(f * 8 + b)) * MF;
      Z[base + k] = make_float2(SCL * (Yx * F1x - Yy * cE), SCL * (Yx * cE + Yy * F1x));
      if (k > 0)
        Z[base + MF - k] = make_float2(SCL * (Yx * F2x + Yy * cE), SCL * (Yx * cE - Yy * F2x));
    }
  } else {
    #pragma unroll
    for (int f = 0; f < 8; ++f) {
      size_t base = ((size_t)(f * 8 + b)) * MF;
      Z[base + k] = make_float2(0.0f, 0.0f);
      Z[base + MF - k] = make_float2(0.0f, 0.0f);
    }
  }
}

// Pointwise: 14 scalars -> MLP -> weighted sum; block partial sums per batch.
// v_pk_fma_f32 (VOP3P dual-FMA) over feature PAIRS: fma instr count 5888->2944
// per point. Weight pairs ride the SGPR operand (wave-uniform s_loads); h1
// lives as 32 x float2 VGPR pairs. Layer-3 stays scalar (W2 is c-strided, no
// contiguous pairs). No __launch_bounds__: (256,5)->VGPR44 and (256,4)->VGPR60
// both made the allocator squeeze to the 8-wave tier with 2.1-2.5x instruction
// bloat (measured R1/R6); natural allocation was clean (1.4x, R0).
__global__ void k_mlpsum(
    const float* __restrict__ conv,
    const float* __restrict__ W0, const float* __restrict__ b0,
    const float* __restrict__ W1, const float* __restrict__ b1,
    const float* __restrict__ W2, const float* __restrict__ b2,
    float* __restrict__ partial) {
  int b = blockIdx.y;
  size_t z = (size_t)blockIdx.x * 256 + threadIdx.x;
  float s0 = conv[(size_t)(0 * 8 + b) * NZTOT + z];
  float s1 = conv[(size_t)(1 * 8 + b) * NZTOT + z];
  float s2 = conv[(size_t)(2 * 8 + b) * NZTOT + z];
  float s3 = conv[(size_t)(3 * 8 + b) * NZTOT + z];
  float o0 = conv[(size_t)(4 * 8 + b) * NZTOT + z];
  float o1 = conv[(size_t)(5 * 8 + b) * NZTOT + z];
  float o2 = conv[(size_t)(6 * 8 + b) * NZTOT + z];
  float o3 = conv[(size_t)(7 * 8 + b) * NZTOT + z];

  v2f sc2[7];
  sc2[0].x = s0;      sc2[0].y = s1;
  sc2[1].x = s2;      sc2[1].y = s3;
  sc2[2].x = o0 * o0; sc2[2].y = o0 * o1;
  sc2[3].x = o0 * o2; sc2[3].y = o0 * o3;
  sc2[4].x = o1 * o1; sc2[4].y = o1 * o2;
  sc2[5].x = o1 * o3; sc2[5].y = o2 * o2;
  sc2[6].x = o2 * o3; sc2[6].y = o3 * o3;
  #define SC_S(c) ((c) & 1 ? sc2[(c) >> 1].y : sc2[(c) >> 1].x)

  /* layer 1: h1[64] as 32 float2; W0 rows are 14 floats (4B-aligned only), so
     build weight pairs from scalar loads. */
  v2f h1p[32];
  #pragma unroll
  for (int o2 = 0; o2 < 32; ++o2) {
    v2f accA, accB;
    accA.x = b0[2 * o2];     accA.y = 0.0f;
    accB.x = b0[2 * o2 + 1]; accB.y = 0.0f;
    #pragma unroll
    for (int j = 0; j < 7; ++j) {
      v2f wA, wB;
      wA.x = W0[(2 * o2) * 14 + 2 * j];     wA.y = W0[(2 * o2) * 14 + 2 * j + 1];
      wB.x = W0[(2 * o2 + 1) * 14 + 2 * j]; wB.y = W0[(2 * o2 + 1) * 14 + 2 * j + 1];
      accA = pkfma_s(wA, sc2[j], accA);
      accB = pkfma_s(wB, sc2[j], accB);
    }
    v2f h;
    h.x = celu_fast(accA.x + accA.y);
    h.y = celu_fast(accB.x + accB.y);
    h1p[o2] = h;
  }

  /* tot init: sum_c sc[c]*b2[c], packed (b2 pairs are 8B-aligned) */
  const v2f* b2p = (const v2f*)b2;
  v2f tot2; tot2.x = 0.0f; tot2.y = 0.0f;
  #pragma unroll
  for (int j = 0; j < 7; ++j) tot2 = pkfma_s(b2p[j], sc2[j], tot2);

  /* layer 2 + fused layer 3: W1 rows are 64 floats -> pairs 8B-aligned. */
  float tot = tot2.x + tot2.y;
  #pragma unroll
  for (int o = 0; o < 64; ++o) {
    v2f acc; acc.x = b1[o]; acc.y = 0.0f;
    const v2f* Wrow = (const v2f*)(W1 + o * 64);
    #pragma unroll
    for (int i = 0; i < 32; ++i) acc = pkfma_s(Wrow[i], h1p[i], acc);
    float h2o = celu_fast(acc.x + acc.y);
    float u = 0.0f;
    #pragma unroll
    for (int c = 0; c < 14; ++c) u = fmaf(W2[c * 64 + o], SC_S(c), u);
    tot = fmaf(h2o, u, tot);
  }
  #undef SC_S

  __shared__ float red[256];
  red[threadIdx.x] = tot;
  __syncthreads();
  for (int s = 128; s > 0; s >>= 1) {
    if (threadIdx.x < s) red[threadIdx.x] += red[threadIdx.x + s];
    __syncthreads();
  }
  if (threadIdx.x == 0) partial[b * 1024 + blockIdx.x] = red[0];
}

__global__ __launch_bounds__(256) void k_reduce(const float* __restrict__ partial,
                                                float* __restrict__ out) {
  __shared__ float red[256];
  int b = blockIdx.x;
  float acc = 0.0f;
  #pragma unroll
  for (int j = 0; j < 4; ++j) acc += partial[b * 1024 + threadIdx.x + 256 * j];
  red[threadIdx.x] = acc;
  __syncthreads();
  for (int s = 128; s > 0; s >>= 1) {
    if (threadIdx.x < s) red[threadIdx.x] += red[threadIdx.x + s];
    __syncthreads();
  }
  if (threadIdx.x == 0) out[b] = DZ_F * red[0];
}

extern "C" void kernel_launch(void* const* d_in, const int* in_sizes, int n_in,
                              void* d_out, int out_size, void* d_ws, size_t ws_size,
                              hipStream_t stream) {
  (void)in_sizes; (void)n_in; (void)out_size; (void)ws_size;
  const float2* nP = (const float2*)d_in[0];   /* n viewed as packed complex, per batch MF */
  const float* wW0 = (const float*)d_in[1];
  const float* wb0 = (const float*)d_in[2];
  const float* wW1 = (const float*)d_in[3];
  const float* wb1 = (const float*)d_in[4];
  const float* wW2 = (const float*)d_in[5];
  const float* wb2 = (const float*)d_in[6];
  const float* fW0 = (const float*)d_in[7];
  const float* fb0 = (const float*)d_in[8];
  const float* fW1 = (const float*)d_in[9];
  const float* fb1 = (const float*)d_in[10];
  const float* fW2 = (const float*)d_in[11];
  const float* fb2 = (const float*)d_in[12];

  /* workspace layout (float2 units): Gf[8*MF] | C[8*MF] | wt[8*KWS] | Z[64*MF] | T[64*MF] | partial */
  float2* Gf = (float2*)d_ws;
  float2* C  = Gf + (size_t)8 * MF;
  float2* wt = C + (size_t)8 * MF;
  float2* Z  = wt + (size_t)8 * KWS;
  float2* T  = Z + (size_t)64 * MF;
  float*  partial = (float*)(T + (size_t)64 * MF);
  float*  conv = (float*)Z;   /* conv aliases Z: Z fully consumed by inverse stage 1 */

  k_wtilde<<<dim3((KCUT + 255) / 256), dim3(256), 0, stream>>>(wW0, wb0, wW1, wb1, wW2, wb2, wt);
  k_fft_stage1<(-1)><<<dim3(32, 8), dim3(256), 0, stream>>>(nP, Gf);
  k_fft_stage2<(-1), true><<<dim3(32, 8), dim3(256), 0, stream>>>(Gf, C);
  k_specmul<<<dim3(257, 8), dim3(256), 0, stream>>>(C, wt, Z);
  k_fft_stage1<1><<<dim3(32, 64), dim3(256), 0, stream>>>(Z, T);
  k_fft_stage2<1, false><<<dim3(32, 64), dim3(256), 0, stream>>>(T, (float2*)conv);
  k_mlpsum<<<dim3(1024, 8), dim3(256), 0, stream>>>(conv, fW0, fb0, fW1, fb1, fW2, fb2, partial);
  k_reduce<<<dim3(8), dim3(256), 0, stream>>>(partial, (float*)d_out);
}